// Round 11
// baseline (423.785 us; speedup 1.0000x reference)
//
#include <hip/hip_runtime.h>
#include <hip/hip_cooperative_groups.h>
#include <math.h>

namespace cg = cooperative_groups;

#define NB 16
#define NS 32
#define NH 768
#define NE 200000
#define NT 200000
#define NR 500
#define NSTEPS 3
#define NWAYS 2

#define HSZ 2048      // frontier hash slots per (gen,b)
#define AHSZ 4096     // accumulator hash slots (final, LDS)
#define BMW 6272      // bitmap u32 words per b
#define GRID 256
#define PCH 16        // prop chunks per b
#define QPB 50000     // int4-quads per b
#define QPC 3125      // QPB/PCH

typedef unsigned int u32;

__device__ __forceinline__ int fhash(int e) { return (int)(((u32)e * 2654435761u) >> 21); }
__device__ __forceinline__ int ahash(int e) { return (int)(((u32)e * 2654435761u) >> 20); }

union SharedU {
    struct { float w[192][68]; float q[NB][196]; } cq;   // 64768 B (max)
    struct { u32 bm[BMW]; } pr;                          // 25088 B
    struct { float ctx[48][68]; } rp;                    // 13056 B
    struct { float cqv[NH]; float sm[NS]; } at;          // 3200 B
    struct { int k[AHSZ]; float v0[AHSZ]; float v1[AHSZ]; } fin; // 49152 B
    struct { float logit[4]; } hp;
};

// rel_dist on the fly: sigmoid(relB + sum of 12 K-chunk partials)
__device__ __forceinline__ float rel_val(const float* __restrict__ part_r,
                                         const float* __restrict__ relB,
                                         int w, int t, int b, int r)
{
    int wt = w * NSTEPS + t;
    float a = relB[w * NR + r];
#pragma unroll
    for (int kc = 0; kc < 12; ++kc)
        a += part_r[(((size_t)kc * 6 + wt) * NB + b) * NR + r];
    return 1.f / (1.f + expf(-a));
}

__global__ __launch_bounds__(256) void fused_kernel(
    const float* __restrict__ heads, const float* __restrict__ qe,
    const float* __restrict__ qwh,  const float* __restrict__ mask,
    const float* __restrict__ stepW, const float* __restrict__ stepB,
    const float* __restrict__ relW, const float* __restrict__ relB,
    const float* __restrict__ hopW, const float* __restrict__ hopB,
    const int* __restrict__ triples, float* __restrict__ out,
    int* keysG, float* valsG, u32* bmG, float* hop,
    float* cqf, float* ctx, float* part_r, int phase)
{
    cg::grid_group grid = cg::this_grid();
    __shared__ SharedU S;
    int tid = threadIdx.x;
    int blk = blockIdx.x;
    int lane = tid & 63, wv = tid >> 6;
    bool all = (phase < 0);

    // ---------- P0: zero hash state (keys+vals+bm) and out ----------
    if (all || phase == 0) {
        const int ZW4 = (4 * NB * HSZ + 4 * NWAYS * NB * HSZ + 4 * NB * BMW) / 4;
        float4 z = make_float4(0.f, 0.f, 0.f, 0.f);
        float4* z1 = (float4*)keysG;
        for (int i = blk * 256 + tid; i < ZW4; i += gridDim.x * 256) z1[i] = z;
        float4* z2 = (float4*)out;
        const int OW4 = NB * NE / 4;
        for (int i = blk * 256 + tid; i < OW4; i += gridDim.x * 256) z2[i] = z;
    }
    if (all) grid.sync();

    // ---------- P1: cq full-K [0,72) | head scan [72,224) | hop [224,256) ----------
    if (all || phase == 1) {
        if (blk < 72) {
            int wt = blk / 12, jc = blk % 12;
            float acc[4] = {0.f, 0.f, 0.f, 0.f};
            for (int kc = 0; kc < 4; ++kc) {
                if (kc) __syncthreads();
                const float* Wbase = stepW + (size_t)wt * NH * NH + (size_t)(kc * 192) * NH + jc * 64;
#pragma unroll
                for (int u = 0; u < 12; ++u) {
                    int f = tid + u * 256;
                    int hh = f >> 4, c4 = (f & 15) * 4;
                    *(float4*)&S.cq.w[hh][c4] = *(const float4*)(Wbase + (size_t)hh * NH + c4);
                }
#pragma unroll
                for (int u = 0; u < 3; ++u) {
                    int f = tid + u * 256;
                    int b = f / 48, c4 = (f % 48) * 4;
                    *(float4*)&S.cq.q[b][c4] = *(const float4*)(qe + (size_t)b * NH + kc * 192 + c4);
                }
                __syncthreads();
#pragma unroll 4
                for (int h4 = 0; h4 < 48; ++h4) {
                    float w0 = S.cq.w[h4 * 4 + 0][lane];
                    float w1 = S.cq.w[h4 * 4 + 1][lane];
                    float w2 = S.cq.w[h4 * 4 + 2][lane];
                    float w3 = S.cq.w[h4 * 4 + 3][lane];
#pragma unroll
                    for (int i = 0; i < 4; ++i) {
                        float4 q = *(const float4*)&S.cq.q[wv * 4 + i][h4 * 4];
                        acc[i] += w0 * q.x + w1 * q.y + w2 * q.z + w3 * q.w;
                    }
                }
            }
            int j = jc * 64 + lane;
#pragma unroll
            for (int i = 0; i < 4; ++i) {
                int b = wv * 4 + i;
                cqf[((size_t)wt * NB + b) * NH + j] = tanhf(acc[i] + stepB[wt * NH + j]);
            }
        } else if (blk < 224) {
            const float4* h4 = (const float4*)heads;
            for (int i = (blk - 72) * 256 + tid; i < NB * NE / 4; i += 152 * 256) {
                float4 v = h4[i];
                float c[4] = { v.x, v.y, v.z, v.w };
#pragma unroll
                for (int k = 0; k < 4; ++k) {
                    if (c[k] != 0.0f) {
                        int idx = i * 4 + k;
                        int b = idx / NE, e = idx % NE;
                        int s = fhash(e);
                        keysG[(size_t)b * HSZ + s] = e + 1;
                        valsG[(size_t)b * HSZ + s] = 1.0f;
                        valsG[(size_t)(NB + b) * HSZ + s] = 1.0f;
                        atomicOr(&bmG[(size_t)b * BMW + (e >> 5)], 1u << (e & 31));
                    }
                }
            }
        } else {
            int wb = blk - 224;
            int w = wb / NB, b = wb % NB;
            if (wv < 3) {
                float a = 0.f;
                for (int h = lane; h < NH; h += 64)
                    a += qe[b * NH + h] * hopW[((size_t)w * NH + h) * NSTEPS + wv];
                for (int off = 32; off; off >>= 1) a += __shfl_down(a, off, 64);
                if (lane == 0) S.hp.logit[wv] = a + hopB[w * NSTEPS + wv];
            }
            __syncthreads();
            if (tid == 0) {
                float mx = fmaxf(S.hp.logit[0], fmaxf(S.hp.logit[1], S.hp.logit[2]));
                float e0 = expf(S.hp.logit[0] - mx), e1 = expf(S.hp.logit[1] - mx), e2 = expf(S.hp.logit[2] - mx);
                float inv = 1.f / (e0 + e1 + e2);
                hop[wb * NSTEPS + 0] = e0 * inv;
                hop[wb * NSTEPS + 1] = e1 * inv;
                hop[wb * NSTEPS + 2] = e2 * inv;
            }
        }
    }
    if (all) grid.sync();

    // ---------- P2: attn (logits -> softmax -> ctx) ----------
    if ((all || phase == 2) && blk < 96) {
        int b = blk % NB, wt = blk / NB;
        for (int j = tid; j < NH; j += 256)
            S.at.cqv[j] = cqf[((size_t)wt * NB + b) * NH + j];
        __syncthreads();
        {
            int s = tid >> 3, l = tid & 7;
            const float* row = qwh + ((size_t)b * NS + s) * NH;
            float a = 0.f;
            for (int h = l; h < NH; h += 8) a += S.at.cqv[h] * row[h];
            a += __shfl_down(a, 4, 8);
            a += __shfl_down(a, 2, 8);
            a += __shfl_down(a, 1, 8);
            if (l == 0) S.at.sm[s] = a;
        }
        __syncthreads();
        if (tid < 64) {
            float lg = (tid < 32) ? S.at.sm[tid] : -1e30f;
            float m = lg;
            for (int off = 16; off; off >>= 1) m = fmaxf(m, __shfl_xor(m, off, 32));
            float ev = expf(lg - m);
            float sum = ev;
            for (int off = 16; off; off >>= 1) sum += __shfl_xor(sum, off, 32);
            float d = ev / sum * ((tid < 32) ? mask[b * NS + tid] : 0.f);
            float sum2 = d;
            for (int off = 16; off; off >>= 1) sum2 += __shfl_xor(sum2, off, 32);
            d = d / (sum2 + 1e-6f);
            if (tid < 32) S.at.sm[tid] = d;
        }
        __syncthreads();
        for (int h = tid; h < NH; h += 256) {
            const float* col = qwh + (size_t)b * NS * NH + h;
            float c = 0.f;
#pragma unroll 8
            for (int s = 0; s < NS; ++s) c += S.at.sm[s] * col[s * NH];
            ctx[((size_t)wt * NB + b) * NH + h] = c;
        }
    }
    if (all) grid.sync();

    // ---------- P3: rel partials (disjoint relW 64k x 64c slices) ----------
    if ((all || phase == 3) && blk < 192) {
        int rc = blk & 7, w = (blk >> 3) & 1, kc = blk >> 4;
#pragma unroll
        for (int u = 0; u < 3; ++u) {
            int f = tid + u * 256;
            int tb = f >> 4, c4 = (f & 15) * 4;
            int t = tb >> 4, b = tb & 15;
            *(float4*)&S.rp.ctx[tb][c4] =
                *(const float4*)(ctx + ((size_t)(w * 3 + t) * NB + b) * NH + kc * 64 + c4);
        }
        __syncthreads();
        int col = rc * 64 + lane;
        int colc = col < NR ? col : NR - 1;
        const float* Wb = relW + (size_t)w * NH * NR + (size_t)(kc * 64) * NR + colc;
        float acc[12];
#pragma unroll
        for (int i = 0; i < 12; ++i) acc[i] = 0.f;
#pragma unroll 4
        for (int h4 = 0; h4 < 16; ++h4) {
            float w0 = Wb[(size_t)(h4 * 4 + 0) * NR];
            float w1 = Wb[(size_t)(h4 * 4 + 1) * NR];
            float w2 = Wb[(size_t)(h4 * 4 + 2) * NR];
            float w3 = Wb[(size_t)(h4 * 4 + 3) * NR];
#pragma unroll
            for (int i = 0; i < 12; ++i) {
                float4 c = *(const float4*)&S.rp.ctx[wv * 12 + i][h4 * 4];
                acc[i] += w0 * c.x + w1 * c.y + w2 * c.z + w3 * c.w;
            }
        }
        if (col < NR) {
#pragma unroll
            for (int i = 0; i < 12; ++i) {
                int tb = wv * 12 + i;
                int t = tb >> 4, b = tb & 15;
                part_r[(((size_t)kc * 6 + (w * 3 + t)) * NB + b) * NR + col] = acc[i];
            }
        }
    }
    if (all) grid.sync();

    // ---------- P4..P6: propagate gen t -> t+1 (rel computed on the fly) ----------
    for (int t = 0; t < NSTEPS; ++t) {
        if (all || phase == 4 + t) {
            int b = blk / PCH, c = blk % PCH;
            const u32* bmIn   = bmG + (size_t)t * NB * BMW;
            const int* keysIn = keysG + (size_t)t * NB * HSZ;
            const float* valsIn = valsG + (size_t)t * NWAYS * NB * HSZ;
            u32* bmOut   = bmG + (size_t)(t + 1) * NB * BMW;
            int* keysOut = keysG + (size_t)(t + 1) * NB * HSZ;
            float* valsOut = valsG + (size_t)(t + 1) * NWAYS * NB * HSZ;

            const u32* g = bmIn + (size_t)b * BMW;
            for (int k = tid; k < BMW; k += 256) S.pr.bm[k] = g[k];
            __syncthreads();

            const int*   kin  = keysIn + (size_t)b * HSZ;
            const float* v0in = valsIn + (size_t)b * HSZ;
            const float* v1in = valsIn + (size_t)(NB + b) * HSZ;
            int*   kout  = keysOut + (size_t)b * HSZ;
            float* v0out = valsOut + (size_t)b * HSZ;
            float* v1out = valsOut + (size_t)(NB + b) * HSZ;
            u32*   bmo   = bmOut + (size_t)b * BMW;

            const int4* tp = (const int4*)(triples + (size_t)b * NT * 3);
            int qend = (c + 1) * QPC;
            for (int q = c * QPC + tid; q < qend; q += 256) {
                int4 x = tp[q * 3 + 0];
                int4 y = tp[q * 3 + 1];
                int4 z = tp[q * 3 + 2];
                int su[4] = { x.x, x.w, y.z, z.y };
                int re[4] = { x.y, y.x, y.w, z.z };
                int ob[4] = { x.z, y.y, z.x, z.w };
#pragma unroll
                for (int k = 0; k < 4; ++k) {
                    int sub = su[k];
                    if ((S.pr.bm[sub >> 5] >> (sub & 31)) & 1u) {
                        int s = fhash(sub);
                        float v0 = 0.f, v1 = 0.f;
                        bool found = false;
                        for (int p = 0; p < HSZ; ++p) {
                            int kk = kin[s];
                            if (kk == 0) break;
                            if (kk == sub + 1) {
                                v0 = fminf(v0in[s], 1.0f);
                                v1 = fminf(v1in[s], 1.0f);
                                found = true;
                                break;
                            }
                            s = (s + 1) & (HSZ - 1);
                        }
                        if (found) {
                            float c0 = v0 * rel_val(part_r, relB, 0, t, b, re[k]);
                            float c1 = v1 * rel_val(part_r, relB, 1, t, b, re[k]);
                            int e = ob[k];
                            int s2 = fhash(e);
                            for (int p = 0; p < HSZ; ++p) {
                                int old = atomicCAS(&kout[s2], 0, e + 1);
                                if (old == 0 || old == e + 1) {
                                    atomicAdd(&v0out[s2], c0);
                                    atomicAdd(&v1out[s2], c1);
                                    if (old == 0) atomicOr(&bmo[e >> 5], 1u << (e & 31));
                                    break;
                                }
                                s2 = (s2 + 1) & (HSZ - 1);
                            }
                        }
                    }
                }
            }
        }
        if (all) grid.sync();
    }

    // ---------- P7: final (hop-weighted accumulate gens 1..3, way product) ----------
    if ((all || phase == 7) && blk < NB) {
        int b = blk;
        for (int i = tid; i < AHSZ; i += 256) { S.fin.k[i] = 0; S.fin.v0[i] = 0.f; S.fin.v1[i] = 0.f; }
        __syncthreads();
        for (int gen = 1; gen <= 3; ++gen) {
            const int* kg = keysG + ((size_t)gen * NB + b) * HSZ;
            const float* vg = valsG + (size_t)gen * NWAYS * NB * HSZ;
            const float* v0 = vg + (size_t)b * HSZ;
            const float* v1 = vg + (size_t)(NB + b) * HSZ;
            float h0 = hop[(0 * NB + b) * NSTEPS + (gen - 1)];
            float h1 = hop[(1 * NB + b) * NSTEPS + (gen - 1)];
            for (int i = tid; i < HSZ; i += 256) {
                int key = kg[i];
                if (key == 0) continue;
                float a0 = h0 * fminf(v0[i], 1.0f);
                float a1 = h1 * fminf(v1[i], 1.0f);
                int s = ahash(key - 1);
                for (int p = 0; p < AHSZ; ++p) {
                    int old = atomicCAS(&S.fin.k[s], 0, key);
                    if (old == 0 || old == key) {
                        atomicAdd(&S.fin.v0[s], a0);
                        atomicAdd(&S.fin.v1[s], a1);
                        break;
                    }
                    s = (s + 1) & (AHSZ - 1);
                }
            }
        }
        __syncthreads();
        for (int i = tid; i < AHSZ; i += 256) {
            int key = S.fin.k[i];
            if (key) out[(size_t)b * NE + (key - 1)] = S.fin.v0[i] * S.fin.v1[i];
        }
    }
}

extern "C" void kernel_launch(void* const* d_in, const int* in_sizes, int n_in,
                              void* d_out, int out_size, void* d_ws, size_t ws_size,
                              hipStream_t stream)
{
    const float* heads  = (const float*)d_in[0];
    const float* qe     = (const float*)d_in[1];
    const float* qwh    = (const float*)d_in[2];
    const float* mask   = (const float*)d_in[3];
    const float* stepW  = (const float*)d_in[4];
    const float* stepB  = (const float*)d_in[5];
    const float* relW   = (const float*)d_in[6];
    const float* relB   = (const float*)d_in[7];
    const float* hopW   = (const float*)d_in[8];
    const float* hopB   = (const float*)d_in[9];
    const int*   triples = (const int*)d_in[10];
    float* out = (float*)d_out;

    // workspace: [keysG 4 gens][valsG 4x2][bmG 4][hop][cqf][ctx][part_r]
    int*   keysG = (int*)d_ws;                                   // 4*16*2048
    float* valsG = (float*)(keysG + 4 * NB * HSZ);               // 4*2*16*2048
    u32*   bmG   = (u32*)(valsG + 4 * NWAYS * NB * HSZ);         // 4*16*6272
    float* hop   = (float*)(bmG + 4 * (size_t)NB * BMW);         // 96
    float* cqf   = hop + NWAYS * NB * NSTEPS;                    // 6*16*768
    float* ctx   = cqf + (size_t)6 * NB * NH;                    // 6*16*768
    float* part_r = ctx + (size_t)6 * NB * NH;                   // 12*6*16*500

    int phase = -1;
    void* args[] = {
        (void*)&heads, (void*)&qe, (void*)&qwh, (void*)&mask,
        (void*)&stepW, (void*)&stepB, (void*)&relW, (void*)&relB,
        (void*)&hopW, (void*)&hopB, (void*)&triples, (void*)&out,
        (void*)&keysG, (void*)&valsG, (void*)&bmG, (void*)&hop,
        (void*)&cqf, (void*)&ctx, (void*)&part_r, (void*)&phase
    };
    hipError_t err = hipLaunchCooperativeKernel((void*)fused_kernel, dim3(GRID), dim3(256),
                                                args, 0, stream);
    if (err != hipSuccess) {
        (void)hipGetLastError();   // clear sticky error; fall back to phased launches
        fused_kernel<<<256, 256, 0, stream>>>(heads, qe, qwh, mask, stepW, stepB, relW, relB,
                                              hopW, hopB, triples, out, keysG, valsG, bmG, hop,
                                              cqf, ctx, part_r, 0);
        fused_kernel<<<256, 256, 0, stream>>>(heads, qe, qwh, mask, stepW, stepB, relW, relB,
                                              hopW, hopB, triples, out, keysG, valsG, bmG, hop,
                                              cqf, ctx, part_r, 1);
        fused_kernel<<<96, 256, 0, stream>>>(heads, qe, qwh, mask, stepW, stepB, relW, relB,
                                             hopW, hopB, triples, out, keysG, valsG, bmG, hop,
                                             cqf, ctx, part_r, 2);
        fused_kernel<<<192, 256, 0, stream>>>(heads, qe, qwh, mask, stepW, stepB, relW, relB,
                                              hopW, hopB, triples, out, keysG, valsG, bmG, hop,
                                              cqf, ctx, part_r, 3);
        for (int t = 0; t < NSTEPS; ++t)
            fused_kernel<<<256, 256, 0, stream>>>(heads, qe, qwh, mask, stepW, stepB, relW, relB,
                                                  hopW, hopB, triples, out, keysG, valsG, bmG, hop,
                                                  cqf, ctx, part_r, 4 + t);
        fused_kernel<<<16, 256, 0, stream>>>(heads, qe, qwh, mask, stepW, stepB, relW, relB,
                                             hopW, hopB, triples, out, keysG, valsG, bmG, hop,
                                             cqf, ctx, part_r, 7);
    }
}

// Round 12
// 403.729 us; speedup vs baseline: 1.0497x; 1.0497x over previous
//
#include <hip/hip_runtime.h>
#include <hip/hip_cooperative_groups.h>
#include <math.h>

namespace cg = cooperative_groups;

#define NB 16
#define NS 32
#define NH 768
#define NE 200000
#define NT 200000
#define NR 500
#define NSTEPS 3
#define NWAYS 2

#define HSZ 2048      // frontier hash slots per (gen,b)
#define AHSZ 4096     // accumulator hash slots (final, LDS)
#define BMW 6272      // bitmap u32 words per b
#define GRID 256
#define NTHR 1024
#define PCH 16        // prop chunks per b
#define QPB 50000     // int4-quads per b
#define QPC 3125      // QPB/PCH

typedef unsigned int u32;

__device__ __forceinline__ int fhash(int e) { return (int)(((u32)e * 2654435761u) >> 21); }
__device__ __forceinline__ int ahash(int e) { return (int)(((u32)e * 2654435761u) >> 20); }

union SharedU {
    struct { float w[192][68]; float q[NB][196]; } cq;   // 64768 B (max)
    struct { u32 bm[BMW]; } pr;                          // 25088 B
    struct { float ctx[48][68]; } rp;                    // 13056 B
    struct { float cqv[NH]; float sm[NS]; } at;          // 3200 B
    struct { int k[AHSZ]; float v0[AHSZ]; float v1[AHSZ]; } fin; // 49152 B
    struct { float logit[4]; } hp;
};

// rel_dist on the fly: sigmoid(relB + sum of 12 K-chunk partials)
__device__ __forceinline__ float rel_val(const float* __restrict__ part_r,
                                         const float* __restrict__ relB,
                                         int w, int t, int b, int r)
{
    int wt = w * NSTEPS + t;
    float a = relB[w * NR + r];
#pragma unroll
    for (int kc = 0; kc < 12; ++kc)
        a += part_r[(((size_t)kc * 6 + wt) * NB + b) * NR + r];
    return 1.f / (1.f + expf(-a));
}

__global__ __launch_bounds__(NTHR, 1) void fused_kernel(
    const float* __restrict__ heads, const float* __restrict__ qe,
    const float* __restrict__ qwh,  const float* __restrict__ mask,
    const float* __restrict__ stepW, const float* __restrict__ stepB,
    const float* __restrict__ relW, const float* __restrict__ relB,
    const float* __restrict__ hopW, const float* __restrict__ hopB,
    const int* __restrict__ triples, float* __restrict__ out,
    int* keysG, float* valsG, u32* bmG, float* hop,
    float* cqf, float* ctx, float* part_r, int phase)
{
    cg::grid_group grid = cg::this_grid();
    __shared__ SharedU S;
    int tid = threadIdx.x;
    int blk = blockIdx.x;
    int lane = tid & 63, wv = tid >> 6;       // wv 0..15
    bool all = (phase < 0);

    // ---------- P0: zero hash state (keys+vals+bm) and out ----------
    if (all || phase == 0) {
        const int ZW4 = (4 * NB * HSZ + 4 * NWAYS * NB * HSZ + 4 * NB * BMW) / 4;
        float4 z = make_float4(0.f, 0.f, 0.f, 0.f);
        float4* z1 = (float4*)keysG;
        for (int i = blk * NTHR + tid; i < ZW4; i += gridDim.x * NTHR) z1[i] = z;
        float4* z2 = (float4*)out;
        const int OW4 = NB * NE / 4;
        for (int i = blk * NTHR + tid; i < OW4; i += gridDim.x * NTHR) z2[i] = z;
    }
    if (all) grid.sync();

    // ---------- P1: cq full-K [0,72) | head scan [72,224) | hop [224,256) ----------
    if (all || phase == 1) {
        if (blk < 72) {
            int wt = blk / 12, jc = blk % 12;
            // wave wv owns b = wv; thread's output col = jc*64 + lane
            float acc = 0.f;
            for (int kc = 0; kc < 4; ++kc) {
                if (kc) __syncthreads();
                const float* Wbase = stepW + (size_t)wt * NH * NH + (size_t)(kc * 192) * NH + jc * 64;
                // stage W: 3072 float4, 3 per thread
#pragma unroll
                for (int u = 0; u < 3; ++u) {
                    int f = tid + u * NTHR;
                    int hh = f >> 4, c4 = (f & 15) * 4;
                    *(float4*)&S.cq.w[hh][c4] = *(const float4*)(Wbase + (size_t)hh * NH + c4);
                }
                // stage qe: 768 float4
                if (tid < 768) {
                    int b = tid / 48, c4 = (tid % 48) * 4;
                    *(float4*)&S.cq.q[b][c4] = *(const float4*)(qe + (size_t)b * NH + kc * 192 + c4);
                }
                __syncthreads();
#pragma unroll 8
                for (int h4 = 0; h4 < 48; ++h4) {
                    float4 q = *(const float4*)&S.cq.q[wv][h4 * 4];   // wave-uniform broadcast
                    acc += S.cq.w[h4 * 4 + 0][lane] * q.x
                         + S.cq.w[h4 * 4 + 1][lane] * q.y
                         + S.cq.w[h4 * 4 + 2][lane] * q.z
                         + S.cq.w[h4 * 4 + 3][lane] * q.w;
                }
            }
            int j = jc * 64 + lane;
            cqf[((size_t)wt * NB + wv) * NH + j] = tanhf(acc + stepB[wt * NH + j]);
        } else if (blk < 224) {
            const float4* h4 = (const float4*)heads;
            for (int i = (blk - 72) * NTHR + tid; i < NB * NE / 4; i += 152 * NTHR) {
                float4 v = h4[i];
                float c[4] = { v.x, v.y, v.z, v.w };
#pragma unroll
                for (int k = 0; k < 4; ++k) {
                    if (c[k] != 0.0f) {
                        int idx = i * 4 + k;
                        int b = idx / NE, e = idx % NE;
                        int s = fhash(e);
                        keysG[(size_t)b * HSZ + s] = e + 1;
                        valsG[(size_t)b * HSZ + s] = 1.0f;
                        valsG[(size_t)(NB + b) * HSZ + s] = 1.0f;
                        atomicOr(&bmG[(size_t)b * BMW + (e >> 5)], 1u << (e & 31));
                    }
                }
            }
        } else {
            int wb = blk - 224;
            int w = wb / NB, b = wb % NB;
            if (wv < 3) {
                float a = 0.f;
                for (int h = lane; h < NH; h += 64)
                    a += qe[b * NH + h] * hopW[((size_t)w * NH + h) * NSTEPS + wv];
                for (int off = 32; off; off >>= 1) a += __shfl_down(a, off, 64);
                if (lane == 0) S.hp.logit[wv] = a + hopB[w * NSTEPS + wv];
            }
            __syncthreads();
            if (tid == 0) {
                float mx = fmaxf(S.hp.logit[0], fmaxf(S.hp.logit[1], S.hp.logit[2]));
                float e0 = expf(S.hp.logit[0] - mx), e1 = expf(S.hp.logit[1] - mx), e2 = expf(S.hp.logit[2] - mx);
                float inv = 1.f / (e0 + e1 + e2);
                hop[wb * NSTEPS + 0] = e0 * inv;
                hop[wb * NSTEPS + 1] = e1 * inv;
                hop[wb * NSTEPS + 2] = e2 * inv;
            }
        }
    }
    if (all) grid.sync();

    // ---------- P2: attn (logits -> softmax -> ctx) ----------
    if ((all || phase == 2) && blk < 96) {
        int b = blk % NB, wt = blk / NB;
        if (tid < NH) S.at.cqv[tid] = cqf[((size_t)wt * NB + b) * NH + tid];
        __syncthreads();
        {
            int s = tid >> 5, l = tid & 31;   // 32 threads per s
            const float* row = qwh + ((size_t)b * NS + s) * NH;
            float a = 0.f;
            for (int h = l; h < NH; h += 32) a += S.at.cqv[h] * row[h];
            for (int off = 16; off; off >>= 1) a += __shfl_down(a, off, 32);
            if (l == 0) S.at.sm[s] = a;
        }
        __syncthreads();
        if (tid < 64) {
            float lg = (tid < 32) ? S.at.sm[tid] : -1e30f;
            float m = lg;
            for (int off = 16; off; off >>= 1) m = fmaxf(m, __shfl_xor(m, off, 32));
            float ev = expf(lg - m);
            float sum = ev;
            for (int off = 16; off; off >>= 1) sum += __shfl_xor(sum, off, 32);
            float d = ev / sum * ((tid < 32) ? mask[b * NS + tid] : 0.f);
            float sum2 = d;
            for (int off = 16; off; off >>= 1) sum2 += __shfl_xor(sum2, off, 32);
            d = d / (sum2 + 1e-6f);
            if (tid < 32) S.at.sm[tid] = d;
        }
        __syncthreads();
        if (tid < NH) {
            const float* col = qwh + (size_t)b * NS * NH + tid;
            float c = 0.f;
#pragma unroll 8
            for (int s = 0; s < NS; ++s) c += S.at.sm[s] * col[s * NH];
            ctx[((size_t)wt * NB + b) * NH + tid] = c;
        }
    }
    if (all) grid.sync();

    // ---------- P3: rel partials (disjoint relW 64k x 64c slices) ----------
    if ((all || phase == 3) && blk < 192) {
        int rc = blk & 7, w = (blk >> 3) & 1, kc = blk >> 4;
        if (tid < 768) {
            int tb = tid >> 4, c4 = (tid & 15) * 4;
            int t = tb >> 4, b = tb & 15;
            *(float4*)&S.rp.ctx[tb][c4] =
                *(const float4*)(ctx + ((size_t)(w * 3 + t) * NB + b) * NH + kc * 64 + c4);
        }
        __syncthreads();
        int col = rc * 64 + lane;
        int colc = col < NR ? col : NR - 1;
        const float* Wb = relW + (size_t)w * NH * NR + (size_t)(kc * 64) * NR + colc;
        float acc[3] = {0.f, 0.f, 0.f};
#pragma unroll 4
        for (int h4 = 0; h4 < 16; ++h4) {
            float w0 = Wb[(size_t)(h4 * 4 + 0) * NR];
            float w1 = Wb[(size_t)(h4 * 4 + 1) * NR];
            float w2 = Wb[(size_t)(h4 * 4 + 2) * NR];
            float w3 = Wb[(size_t)(h4 * 4 + 3) * NR];
#pragma unroll
            for (int i = 0; i < 3; ++i) {
                float4 c = *(const float4*)&S.rp.ctx[wv * 3 + i][h4 * 4];
                acc[i] += w0 * c.x + w1 * c.y + w2 * c.z + w3 * c.w;
            }
        }
        if (col < NR) {
#pragma unroll
            for (int i = 0; i < 3; ++i) {
                int tb = wv * 3 + i;
                int t = tb >> 4, b = tb & 15;
                part_r[(((size_t)kc * 6 + (w * 3 + t)) * NB + b) * NR + col] = acc[i];
            }
        }
    }
    if (all) grid.sync();

    // ---------- P4..P6: propagate gen t -> t+1 (rel computed on the fly) ----------
    for (int t = 0; t < NSTEPS; ++t) {
        if (all || phase == 4 + t) {
            int b = blk / PCH, c = blk % PCH;
            const u32* bmIn   = bmG + (size_t)t * NB * BMW;
            const int* keysIn = keysG + (size_t)t * NB * HSZ;
            const float* valsIn = valsG + (size_t)t * NWAYS * NB * HSZ;
            u32* bmOut   = bmG + (size_t)(t + 1) * NB * BMW;
            int* keysOut = keysG + (size_t)(t + 1) * NB * HSZ;
            float* valsOut = valsG + (size_t)(t + 1) * NWAYS * NB * HSZ;

            const u32* g = bmIn + (size_t)b * BMW;
            for (int k = tid; k < BMW; k += NTHR) S.pr.bm[k] = g[k];
            __syncthreads();

            const int*   kin  = keysIn + (size_t)b * HSZ;
            const float* v0in = valsIn + (size_t)b * HSZ;
            const float* v1in = valsIn + (size_t)(NB + b) * HSZ;
            int*   kout  = keysOut + (size_t)b * HSZ;
            float* v0out = valsOut + (size_t)b * HSZ;
            float* v1out = valsOut + (size_t)(NB + b) * HSZ;
            u32*   bmo   = bmOut + (size_t)b * BMW;

            const int4* tp = (const int4*)(triples + (size_t)b * NT * 3);
            int qend = (c + 1) * QPC;
            for (int q = c * QPC + tid; q < qend; q += NTHR) {
                int4 x = tp[q * 3 + 0];
                int4 y = tp[q * 3 + 1];
                int4 z = tp[q * 3 + 2];
                int su[4] = { x.x, x.w, y.z, z.y };
                int re[4] = { x.y, y.x, y.w, z.z };
                int ob[4] = { x.z, y.y, z.x, z.w };
#pragma unroll
                for (int k = 0; k < 4; ++k) {
                    int sub = su[k];
                    if ((S.pr.bm[sub >> 5] >> (sub & 31)) & 1u) {
                        int s = fhash(sub);
                        float v0 = 0.f, v1 = 0.f;
                        bool found = false;
                        for (int p = 0; p < HSZ; ++p) {
                            int kk = kin[s];
                            if (kk == 0) break;
                            if (kk == sub + 1) {
                                v0 = fminf(v0in[s], 1.0f);
                                v1 = fminf(v1in[s], 1.0f);
                                found = true;
                                break;
                            }
                            s = (s + 1) & (HSZ - 1);
                        }
                        if (found) {
                            float c0 = v0 * rel_val(part_r, relB, 0, t, b, re[k]);
                            float c1 = v1 * rel_val(part_r, relB, 1, t, b, re[k]);
                            int e = ob[k];
                            int s2 = fhash(e);
                            for (int p = 0; p < HSZ; ++p) {
                                int old = atomicCAS(&kout[s2], 0, e + 1);
                                if (old == 0 || old == e + 1) {
                                    atomicAdd(&v0out[s2], c0);
                                    atomicAdd(&v1out[s2], c1);
                                    if (old == 0) atomicOr(&bmo[e >> 5], 1u << (e & 31));
                                    break;
                                }
                                s2 = (s2 + 1) & (HSZ - 1);
                            }
                        }
                    }
                }
            }
        }
        if (all) grid.sync();
    }

    // ---------- P7: final (hop-weighted accumulate gens 1..3, way product) ----------
    if ((all || phase == 7) && blk < NB) {
        int b = blk;
        for (int i = tid; i < AHSZ; i += NTHR) { S.fin.k[i] = 0; S.fin.v0[i] = 0.f; S.fin.v1[i] = 0.f; }
        __syncthreads();
        for (int gen = 1; gen <= 3; ++gen) {
            const int* kg = keysG + ((size_t)gen * NB + b) * HSZ;
            const float* vg = valsG + (size_t)gen * NWAYS * NB * HSZ;
            const float* v0 = vg + (size_t)b * HSZ;
            const float* v1 = vg + (size_t)(NB + b) * HSZ;
            float h0 = hop[(0 * NB + b) * NSTEPS + (gen - 1)];
            float h1 = hop[(1 * NB + b) * NSTEPS + (gen - 1)];
            for (int i = tid; i < HSZ; i += NTHR) {
                int key = kg[i];
                if (key == 0) continue;
                float a0 = h0 * fminf(v0[i], 1.0f);
                float a1 = h1 * fminf(v1[i], 1.0f);
                int s = ahash(key - 1);
                for (int p = 0; p < AHSZ; ++p) {
                    int old = atomicCAS(&S.fin.k[s], 0, key);
                    if (old == 0 || old == key) {
                        atomicAdd(&S.fin.v0[s], a0);
                        atomicAdd(&S.fin.v1[s], a1);
                        break;
                    }
                    s = (s + 1) & (AHSZ - 1);
                }
            }
        }
        __syncthreads();
        for (int i = tid; i < AHSZ; i += NTHR) {
            int key = S.fin.k[i];
            if (key) out[(size_t)b * NE + (key - 1)] = S.fin.v0[i] * S.fin.v1[i];
        }
    }
}

extern "C" void kernel_launch(void* const* d_in, const int* in_sizes, int n_in,
                              void* d_out, int out_size, void* d_ws, size_t ws_size,
                              hipStream_t stream)
{
    const float* heads  = (const float*)d_in[0];
    const float* qe     = (const float*)d_in[1];
    const float* qwh    = (const float*)d_in[2];
    const float* mask   = (const float*)d_in[3];
    const float* stepW  = (const float*)d_in[4];
    const float* stepB  = (const float*)d_in[5];
    const float* relW   = (const float*)d_in[6];
    const float* relB   = (const float*)d_in[7];
    const float* hopW   = (const float*)d_in[8];
    const float* hopB   = (const float*)d_in[9];
    const int*   triples = (const int*)d_in[10];
    float* out = (float*)d_out;

    // workspace: [keysG 4 gens][valsG 4x2][bmG 4][hop][cqf][ctx][part_r]
    int*   keysG = (int*)d_ws;                                   // 4*16*2048
    float* valsG = (float*)(keysG + 4 * NB * HSZ);               // 4*2*16*2048
    u32*   bmG   = (u32*)(valsG + 4 * NWAYS * NB * HSZ);         // 4*16*6272
    float* hop   = (float*)(bmG + 4 * (size_t)NB * BMW);         // 96
    float* cqf   = hop + NWAYS * NB * NSTEPS;                    // 6*16*768
    float* ctx   = cqf + (size_t)6 * NB * NH;                    // 6*16*768
    float* part_r = ctx + (size_t)6 * NB * NH;                   // 12*6*16*500

    int phase = -1;
    void* args[] = {
        (void*)&heads, (void*)&qe, (void*)&qwh, (void*)&mask,
        (void*)&stepW, (void*)&stepB, (void*)&relW, (void*)&relB,
        (void*)&hopW, (void*)&hopB, (void*)&triples, (void*)&out,
        (void*)&keysG, (void*)&valsG, (void*)&bmG, (void*)&hop,
        (void*)&cqf, (void*)&ctx, (void*)&part_r, (void*)&phase
    };
    hipError_t err = hipLaunchCooperativeKernel((void*)fused_kernel, dim3(GRID), dim3(NTHR),
                                                args, 0, stream);
    if (err != hipSuccess) {
        (void)hipGetLastError();   // clear sticky error; fall back to phased launches
        fused_kernel<<<256, NTHR, 0, stream>>>(heads, qe, qwh, mask, stepW, stepB, relW, relB,
                                               hopW, hopB, triples, out, keysG, valsG, bmG, hop,
                                               cqf, ctx, part_r, 0);
        fused_kernel<<<256, NTHR, 0, stream>>>(heads, qe, qwh, mask, stepW, stepB, relW, relB,
                                               hopW, hopB, triples, out, keysG, valsG, bmG, hop,
                                               cqf, ctx, part_r, 1);
        fused_kernel<<<96, NTHR, 0, stream>>>(heads, qe, qwh, mask, stepW, stepB, relW, relB,
                                              hopW, hopB, triples, out, keysG, valsG, bmG, hop,
                                              cqf, ctx, part_r, 2);
        fused_kernel<<<192, NTHR, 0, stream>>>(heads, qe, qwh, mask, stepW, stepB, relW, relB,
                                               hopW, hopB, triples, out, keysG, valsG, bmG, hop,
                                               cqf, ctx, part_r, 3);
        for (int t = 0; t < NSTEPS; ++t)
            fused_kernel<<<256, NTHR, 0, stream>>>(heads, qe, qwh, mask, stepW, stepB, relW, relB,
                                                   hopW, hopB, triples, out, keysG, valsG, bmG, hop,
                                                   cqf, ctx, part_r, 4 + t);
        fused_kernel<<<16, NTHR, 0, stream>>>(heads, qe, qwh, mask, stepW, stepB, relW, relB,
                                              hopW, hopB, triples, out, keysG, valsG, bmG, hop,
                                              cqf, ctx, part_r, 7);
    }
}

// Round 13
// 287.632 us; speedup vs baseline: 1.4734x; 1.4036x over previous
//
#include <hip/hip_runtime.h>
#include <math.h>

#define NB 16
#define NS 32
#define NH 768
#define NE 200000
#define NT 200000
#define NR 500
#define NSTEPS 3
#define NWAYS 2

#define HSZ 2048      // frontier hash slots per (gen,b)
#define AHSZ 4096     // accumulator hash slots (final, LDS)
#define BMW 6272      // bitmap u32 words per b
#define PCHUNK 40     // prop chunks per b
#define QPC 1250      // (NT/4)/PCHUNK

typedef unsigned int u32;

__device__ __forceinline__ int fhash(int e) { return (int)(((u32)e * 2654435761u) >> 21); }
__device__ __forceinline__ int ahash(int e) { return (int)(((u32)e * 2654435761u) >> 20); }

// rel_dist on the fly: sigmoid(relB + sum of 12 K-chunk partials)
__device__ __forceinline__ float rel_val(const float* __restrict__ part_r,
                                         const float* __restrict__ relB,
                                         int w, int t, int b, int r)
{
    int wt = w * NSTEPS + t;
    float a = relB[w * NR + r];
#pragma unroll
    for (int kc = 0; kc < 12; ++kc)
        a += part_r[(((size_t)kc * 6 + wt) * NB + b) * NR + r];
    return 1.f / (1.f + expf(-a));
}

union PrepShared {
    struct { float w[192][68]; float q[NB][196]; } cq;   // 64768 B
    float hp[4];
};

// ============ prep: cq_part | head(bm0) | zero gens1-3 | hop | zero out ============
// grid: [0,288) cq | [288,304) head | [304,400) zero | [400,432) hop | [432,688) out-zero
__global__ __launch_bounds__(256) void prep_kernel(
    const float* __restrict__ qe, const float* __restrict__ stepW,
    const float* __restrict__ heads,
    const float* __restrict__ hopW, const float* __restrict__ hopB,
    float* __restrict__ part, int* __restrict__ keysG, float* __restrict__ valsG,
    u32* __restrict__ bmG, float* __restrict__ hop, float* __restrict__ out)
{
    __shared__ PrepShared S;
    int tid = threadIdx.x;
    int blk = blockIdx.x;
    int lane = tid & 63, wv = tid >> 6;

    if (blk < 288) {
        // ---- cq partials: disjoint 192x64 stepW slices, b batched ----
        int jc = blk % 12;
        int wt = (blk / 12) % 6;
        int kc = blk / 72;
        const float* Wbase = stepW + (size_t)wt * NH * NH + (size_t)(kc * 192) * NH + jc * 64;
#pragma unroll
        for (int u = 0; u < 12; ++u) {
            int f = tid + u * 256;
            int hh = f >> 4, c4 = (f & 15) * 4;
            *(float4*)&S.cq.w[hh][c4] = *(const float4*)(Wbase + (size_t)hh * NH + c4);
        }
#pragma unroll
        for (int u = 0; u < 3; ++u) {
            int f = tid + u * 256;
            int b = f / 48, c4 = (f % 48) * 4;
            *(float4*)&S.cq.q[b][c4] = *(const float4*)(qe + (size_t)b * NH + kc * 192 + c4);
        }
        __syncthreads();
        float acc[4] = {0.f, 0.f, 0.f, 0.f};
#pragma unroll 4
        for (int h4 = 0; h4 < 48; ++h4) {
            float w0 = S.cq.w[h4 * 4 + 0][lane];
            float w1 = S.cq.w[h4 * 4 + 1][lane];
            float w2 = S.cq.w[h4 * 4 + 2][lane];
            float w3 = S.cq.w[h4 * 4 + 3][lane];
#pragma unroll
            for (int i = 0; i < 4; ++i) {
                float4 q = *(const float4*)&S.cq.q[wv * 4 + i][h4 * 4];
                acc[i] += w0 * q.x + w1 * q.y + w2 * q.z + w3 * q.w;
            }
        }
#pragma unroll
        for (int i = 0; i < 4; ++i) {
            int b = wv * 4 + i;
            part[(((size_t)kc * 6 + wt) * NB + b) * NH + jc * 64 + lane] = acc[i];
        }
    } else if (blk < 304) {
        // ---- head: zero own b's bm0 slice, then scan heads row, set bit ----
        int b = blk - 288;
        u32* bm = bmG + (size_t)b * BMW;
        for (int k = tid; k < BMW; k += 256) bm[k] = 0u;
        __syncthreads();
        const float4* row = (const float4*)(heads + (size_t)b * NE);
        for (int i = tid; i < NE / 4; i += 256) {
            float4 v = row[i];
            float c[4] = { v.x, v.y, v.z, v.w };
#pragma unroll
            for (int k = 0; k < 4; ++k) {
                if (c[k] != 0.0f) {
                    int e = i * 4 + k;
                    atomicOr(&bm[e >> 5], 1u << (e & 31));
                }
            }
        }
    } else if (blk < 400) {
        // ---- zero gens 1..3: keys, vals, bitmaps ----
        int zb = blk - 304;
        float4 z = make_float4(0.f, 0.f, 0.f, 0.f);
        float4* k1 = (float4*)(keysG + NB * HSZ);            // 3*16*2048 ints  = 24576 f4
        float4* v1 = (float4*)(valsG + NWAYS * NB * HSZ);    // 3*2*16*2048 f   = 49152 f4
        float4* b1 = (float4*)(bmG + (size_t)NB * BMW);      // 3*16*6272 u32   = 75264 f4
        for (int i = zb * 256 + tid; i < 24576; i += 96 * 256) k1[i] = z;
        for (int i = zb * 256 + tid; i < 49152; i += 96 * 256) v1[i] = z;
        for (int i = zb * 256 + tid; i < 75264; i += 96 * 256) b1[i] = z;
    } else if (blk < 432) {
        // ---- hop attention ----
        int wb = blk - 400;
        int w = wb / NB, b = wb % NB;
        if (wv < 3) {
            float a = 0.f;
            for (int h = lane; h < NH; h += 64)
                a += qe[b * NH + h] * hopW[((size_t)w * NH + h) * NSTEPS + wv];
            for (int off = 32; off; off >>= 1) a += __shfl_down(a, off, 64);
            if (lane == 0) S.hp[wv] = a + hopB[w * NSTEPS + wv];
        }
        __syncthreads();
        if (tid == 0) {
            float mx = fmaxf(S.hp[0], fmaxf(S.hp[1], S.hp[2]));
            float e0 = expf(S.hp[0] - mx), e1 = expf(S.hp[1] - mx), e2 = expf(S.hp[2] - mx);
            float inv = 1.f / (e0 + e1 + e2);
            hop[wb * NSTEPS + 0] = e0 * inv;
            hop[wb * NSTEPS + 1] = e1 * inv;
            hop[wb * NSTEPS + 2] = e2 * inv;
        }
    } else {
        // ---- zero out ----
        int ob = blk - 432;
        float4 z = make_float4(0.f, 0.f, 0.f, 0.f);
        float4* o4 = (float4*)out;
        for (int i = ob * 256 + tid; i < NB * NE / 4; i += 256 * 256) o4[i] = z;
    }
}

// ===== attn: reduce cq partials -> tanh -> logits -> softmax -> ctx =====
__global__ __launch_bounds__(256) void attn_kernel(
    const float* __restrict__ part, const float* __restrict__ stepB,
    const float* __restrict__ qwh, const float* __restrict__ mask,
    float* __restrict__ ctx)
{
    int b = blockIdx.x % NB;
    int wt = blockIdx.x / NB;

    __shared__ float s_cq[NH];
    __shared__ float s_sm[NS];

    int tid = threadIdx.x;

    for (int j = tid; j < NH; j += 256) {
        float a = stepB[wt * NH + j];
#pragma unroll
        for (int kc = 0; kc < 4; ++kc)
            a += part[(((size_t)kc * 6 + wt) * NB + b) * NH + j];
        s_cq[j] = tanhf(a);
    }
    __syncthreads();

    {
        int s = tid >> 3, l = tid & 7;
        const float* row = qwh + ((size_t)b * NS + s) * NH;
        float a = 0.f;
        for (int h = l; h < NH; h += 8) a += s_cq[h] * row[h];
        a += __shfl_down(a, 4, 8);
        a += __shfl_down(a, 2, 8);
        a += __shfl_down(a, 1, 8);
        if (l == 0) s_sm[s] = a;
    }
    __syncthreads();

    if (tid < 64) {
        float lg = (tid < 32) ? s_sm[tid] : -1e30f;
        float m = lg;
        for (int off = 16; off; off >>= 1) m = fmaxf(m, __shfl_xor(m, off, 32));
        float ev = expf(lg - m);
        float sum = ev;
        for (int off = 16; off; off >>= 1) sum += __shfl_xor(sum, off, 32);
        float d = ev / sum * ((tid < 32) ? mask[b * NS + tid] : 0.f);
        float sum2 = d;
        for (int off = 16; off; off >>= 1) sum2 += __shfl_xor(sum2, off, 32);
        d = d / (sum2 + 1e-6f);
        if (tid < 32) s_sm[tid] = d;
    }
    __syncthreads();

    for (int h = tid; h < NH; h += 256) {
        const float* col = qwh + (size_t)b * NS * NH + h;
        float c = 0.f;
#pragma unroll 8
        for (int s = 0; s < NS; ++s) c += s_sm[s] * col[s * NH];
        ctx[((size_t)wt * NB + b) * NH + h] = c;
    }
}

// ================= rel partials: disjoint relW 64k x 64c slices =================
__global__ __launch_bounds__(256) void rel_part_kernel(
    const float* __restrict__ ctx, const float* __restrict__ relW,
    float* __restrict__ part_r)
{
    int blk = blockIdx.x;              // kc*16 + w*8 + rc
    int rc = blk & 7;
    int w  = (blk >> 3) & 1;
    int kc = blk >> 4;

    __shared__ float s_ctx[48][68];

    int tid = threadIdx.x;
    int lane = tid & 63, wv = tid >> 6;

#pragma unroll
    for (int u = 0; u < 3; ++u) {
        int f = tid + u * 256;
        int tb = f >> 4, c4 = (f & 15) * 4;
        int t = tb >> 4, b = tb & 15;
        float4 v = *(const float4*)(ctx + ((size_t)(w * 3 + t) * NB + b) * NH + kc * 64 + c4);
        *(float4*)&s_ctx[tb][c4] = v;
    }
    __syncthreads();

    int col = rc * 64 + lane;
    int colc = col < NR ? col : NR - 1;
    const float* Wb = relW + (size_t)w * NH * NR + (size_t)(kc * 64) * NR + colc;

    float acc[12];
#pragma unroll
    for (int i = 0; i < 12; ++i) acc[i] = 0.f;

#pragma unroll 4
    for (int h4 = 0; h4 < 16; ++h4) {
        float w0 = Wb[(size_t)(h4 * 4 + 0) * NR];
        float w1 = Wb[(size_t)(h4 * 4 + 1) * NR];
        float w2 = Wb[(size_t)(h4 * 4 + 2) * NR];
        float w3 = Wb[(size_t)(h4 * 4 + 3) * NR];
#pragma unroll
        for (int i = 0; i < 12; ++i) {
            float4 c = *(const float4*)&s_ctx[wv * 12 + i][h4 * 4];
            acc[i] += w0 * c.x + w1 * c.y + w2 * c.z + w3 * c.w;
        }
    }
    if (col < NR) {
#pragma unroll
        for (int i = 0; i < 12; ++i) {
            int tb = wv * 12 + i;
            int t = tb >> 4, b = tb & 15;
            part_r[(((size_t)kc * 6 + (w * 3 + t)) * NB + b) * NR + col] = acc[i];
        }
    }
}

// ================= propagate gen t -> gen t+1 (rel on the fly) =================
// FIRST=1: gen0 is the one-hot head frontier; bitmap hit implies value 1.0 (no hash).
template <int FIRST>
__global__ __launch_bounds__(256) void prop_kernel(
    const int* __restrict__ triples,
    const u32* __restrict__ bmIn, const int* __restrict__ keysIn, const float* __restrict__ valsIn,
    u32* __restrict__ bmOut, int* __restrict__ keysOut, float* __restrict__ valsOut,
    const float* __restrict__ part_r, const float* __restrict__ relB, int t)
{
    __shared__ u32 s_bm[BMW];
    int b = blockIdx.x / PCHUNK;
    int c = blockIdx.x % PCHUNK;
    const u32* g = bmIn + (size_t)b * BMW;
    for (int k = threadIdx.x; k < BMW; k += 256) s_bm[k] = g[k];
    __syncthreads();

    const int*   kin  = keysIn  + (size_t)b * HSZ;
    const float* v0in = valsIn  + (size_t)b * HSZ;
    const float* v1in = valsIn  + (size_t)(NB + b) * HSZ;
    int*   kout  = keysOut + (size_t)b * HSZ;
    float* v0out = valsOut + (size_t)b * HSZ;
    float* v1out = valsOut + (size_t)(NB + b) * HSZ;
    u32*   bmo   = bmOut + (size_t)b * BMW;

    const int4* tp = (const int4*)(triples + (size_t)b * NT * 3);
    int qend = (c + 1) * QPC;
    for (int q = c * QPC + threadIdx.x; q < qend; q += 256) {
        int4 x = tp[q * 3 + 0];
        int4 y = tp[q * 3 + 1];
        int4 z = tp[q * 3 + 2];
        int su[4] = { x.x, x.w, y.z, z.y };
        int re[4] = { x.y, y.x, y.w, z.z };
        int ob[4] = { x.z, y.y, z.x, z.w };
#pragma unroll
        for (int k = 0; k < 4; ++k) {
            int sub = su[k];
            if ((s_bm[sub >> 5] >> (sub & 31)) & 1u) {
                float v0, v1;
                bool found;
                if (FIRST) {
                    v0 = 1.0f; v1 = 1.0f; found = true;
                } else {
                    v0 = 0.f; v1 = 0.f; found = false;
                    int s = fhash(sub);
                    for (int p = 0; p < HSZ; ++p) {
                        int kk = kin[s];
                        if (kk == 0) break;
                        if (kk == sub + 1) {
                            v0 = fminf(v0in[s], 1.0f);
                            v1 = fminf(v1in[s], 1.0f);
                            found = true;
                            break;
                        }
                        s = (s + 1) & (HSZ - 1);
                    }
                }
                if (found) {
                    float c0 = v0 * rel_val(part_r, relB, 0, t, b, re[k]);
                    float c1 = v1 * rel_val(part_r, relB, 1, t, b, re[k]);
                    int e = ob[k];
                    int s2 = fhash(e);
                    for (int p = 0; p < HSZ; ++p) {
                        int old = atomicCAS(&kout[s2], 0, e + 1);
                        if (old == 0 || old == e + 1) {
                            atomicAdd(&v0out[s2], c0);
                            atomicAdd(&v1out[s2], c1);
                            if (old == 0) atomicOr(&bmo[e >> 5], 1u << (e & 31));
                            break;
                        }
                        s2 = (s2 + 1) & (HSZ - 1);
                    }
                }
            }
        }
    }
}

// ================= final: hop-weighted accumulate gens 1..3, way product =================
__global__ __launch_bounds__(256) void final_kernel(
    const int* __restrict__ keysG, const float* __restrict__ valsG,
    const float* __restrict__ hop, float* __restrict__ out)
{
    __shared__ int s_k[AHSZ];
    __shared__ float s_v0[AHSZ];
    __shared__ float s_v1[AHSZ];
    int b = blockIdx.x;
    for (int i = threadIdx.x; i < AHSZ; i += 256) { s_k[i] = 0; s_v0[i] = 0.f; s_v1[i] = 0.f; }
    __syncthreads();
    for (int gen = 1; gen <= 3; ++gen) {
        const int* kg = keysG + ((size_t)gen * NB + b) * HSZ;
        const float* vg = valsG + (size_t)gen * NWAYS * NB * HSZ;
        const float* v0 = vg + (size_t)b * HSZ;
        const float* v1 = vg + (size_t)(NB + b) * HSZ;
        float h0 = hop[(0 * NB + b) * NSTEPS + (gen - 1)];
        float h1 = hop[(1 * NB + b) * NSTEPS + (gen - 1)];
        for (int i = threadIdx.x; i < HSZ; i += 256) {
            int key = kg[i];
            if (key == 0) continue;
            float a0 = h0 * fminf(v0[i], 1.0f);
            float a1 = h1 * fminf(v1[i], 1.0f);
            int s = ahash(key - 1);
            for (int p = 0; p < AHSZ; ++p) {
                int old = atomicCAS(&s_k[s], 0, key);
                if (old == 0 || old == key) {
                    atomicAdd(&s_v0[s], a0);
                    atomicAdd(&s_v1[s], a1);
                    break;
                }
                s = (s + 1) & (AHSZ - 1);
            }
        }
    }
    __syncthreads();
    for (int i = threadIdx.x; i < AHSZ; i += 256) {
        int key = s_k[i];
        if (key) out[(size_t)b * NE + (key - 1)] = s_v0[i] * s_v1[i];
    }
}

extern "C" void kernel_launch(void* const* d_in, const int* in_sizes, int n_in,
                              void* d_out, int out_size, void* d_ws, size_t ws_size,
                              hipStream_t stream)
{
    const float* heads  = (const float*)d_in[0];
    const float* qe     = (const float*)d_in[1];
    const float* qwh    = (const float*)d_in[2];
    const float* mask   = (const float*)d_in[3];
    const float* stepW  = (const float*)d_in[4];
    const float* stepB  = (const float*)d_in[5];
    const float* relW   = (const float*)d_in[6];
    const float* relB   = (const float*)d_in[7];
    const float* hopW   = (const float*)d_in[8];
    const float* hopB   = (const float*)d_in[9];
    const int*   triples = (const int*)d_in[10];
    float* out = (float*)d_out;

    // workspace: [keysG 4 gens][valsG 4x2][bmG 4][hop][part][ctx][part_r]
    int*   keysG = (int*)d_ws;                                   // 4*16*2048
    float* valsG = (float*)(keysG + 4 * NB * HSZ);               // 4*2*16*2048
    u32*   bmG   = (u32*)(valsG + 4 * NWAYS * NB * HSZ);         // 4*16*6272
    float* hop   = (float*)(bmG + 4 * (size_t)NB * BMW);         // 96
    float* part  = hop + NWAYS * NB * NSTEPS;                    // 4*6*16*768
    float* ctx   = part + (size_t)4 * 6 * NB * NH;               // 6*16*768
    float* part_r = ctx + (size_t)6 * NB * NH;                   // 12*6*16*500

    // 1. prep: cq_part | head/bm0 | zero gens1-3 | hop | zero out
    prep_kernel<<<688, 256, 0, stream>>>(qe, stepW, heads, hopW, hopB,
                                         part, keysG, valsG, bmG, hop, out);
    // 2. attn
    attn_kernel<<<96, 256, 0, stream>>>(part, stepB, qwh, mask, ctx);
    // 3. rel partials
    rel_part_kernel<<<192, 256, 0, stream>>>(ctx, relW, part_r);
    // 4-6. propagate
    prop_kernel<1><<<NB * PCHUNK, 256, 0, stream>>>(
        triples, bmG, keysG, valsG,
        bmG + (size_t)1 * NB * BMW, keysG + (size_t)1 * NB * HSZ, valsG + (size_t)1 * NWAYS * NB * HSZ,
        part_r, relB, 0);
    prop_kernel<0><<<NB * PCHUNK, 256, 0, stream>>>(
        triples,
        bmG + (size_t)1 * NB * BMW, keysG + (size_t)1 * NB * HSZ, valsG + (size_t)1 * NWAYS * NB * HSZ,
        bmG + (size_t)2 * NB * BMW, keysG + (size_t)2 * NB * HSZ, valsG + (size_t)2 * NWAYS * NB * HSZ,
        part_r, relB, 1);
    prop_kernel<0><<<NB * PCHUNK, 256, 0, stream>>>(
        triples,
        bmG + (size_t)2 * NB * BMW, keysG + (size_t)2 * NB * HSZ, valsG + (size_t)2 * NWAYS * NB * HSZ,
        bmG + (size_t)3 * NB * BMW, keysG + (size_t)3 * NB * HSZ, valsG + (size_t)3 * NWAYS * NB * HSZ,
        part_r, relB, 2);
    // 7. final
    final_kernel<<<NB, 256, 0, stream>>>(keysG, valsG, hop, out);
}